// Round 5
// baseline (493.639 us; speedup 1.0000x reference)
//
#include <hip/hip_runtime.h>
#include <math.h>

// SparseMoEALU R5: 4 rows/wave (2 stacked M=16 tiles, each weight frag -> 2
// MFMAs), XCD-affinity op->block mapping (L2-resident weights), ticket-based
// bucketing (memset + 2 prep kernels). Barrier-free main kernel.

typedef __bf16 bfrag  __attribute__((ext_vector_type(8)));
typedef __bf16 bf16x4 __attribute__((ext_vector_type(4)));
typedef float  f32x4  __attribute__((ext_vector_type(4)));

#define MFMA16(a,b,c) __builtin_amdgcn_mfma_f32_16x16x32_bf16((a),(b),(c),0,0,0)

constexpr int NB = 16384, NOPS = 37, OP_START = 16;
constexpr int CAP = 1024;            // bucket capacity (expect ~443 +- ~21)

// ws ints: cnt[64] @0 (memset 256B), rowIdx buckets @64
constexpr int WS_CNT    = 0;
constexpr int WS_ROWIDX = 64;
constexpr int WS_BYTES_BUCKETS = (64 + NOPS * CAP) * 4;   // 151808 B
// weight region base (16B aligned)
constexpr int WB_BYTE = 151808;

// bf16 elem offsets in frag-major weight region
constexpr int OFF_QKV = 0;         // 3 x 4096   (Q,K,V)
constexpr int OFF_I   = 12288;     // 37 x (W1 8192 | W2 8192)
constexpr int OFF_C   = 618496;
constexpr int OFF_F   = 1224704;
constexpr int OFF_D   = 1830912;   // 16 x 16384
constexpr int OFF_M   = 2093056;

// ---------------- prep kernels ----------------

// one wave per row: argmax over opcode one-hot; ticket-bucket the row id
__global__ void k_route(const float* __restrict__ x, int* __restrict__ cnt,
                        int* __restrict__ rowIdx) {
    int wave = threadIdx.x >> 6, lane = threadIdx.x & 63;
    int row = blockIdx.x * 4 + wave;
    if (row >= NB) return;
    float av = (lane < NOPS) ? x[(size_t)row * 512 + OP_START + lane] : -INFINITY;
    int ai = lane;
    #pragma unroll
    for (int s = 1; s < 64; s <<= 1) {
        float ov = __shfl_xor(av, s);
        int   oi = __shfl_xor(ai, s);
        if (ov > av || (ov == av && oi < ai)) { av = ov; ai = oi; }
    }
    if (lane == 0) {
        int t = atomicAdd(&cnt[ai], 1);
        if (t > CAP - 1) t = CAP - 1;
        rowIdx[ai * CAP + t] = row;
    }
}

// frag-major weight transform (identical math to R4's verified version)
__global__ void k_wt(const float* __restrict__ Wi1, const float* __restrict__ Wi2,
                     const float* __restrict__ Wq,  const float* __restrict__ Wk,
                     const float* __restrict__ Wv,
                     const float* __restrict__ Wc1, const float* __restrict__ Wc2,
                     const float* __restrict__ Wd1, const float* __restrict__ Wd2,
                     const float* __restrict__ Wm1, const float* __restrict__ Wm2,
                     const float* __restrict__ Wf1, const float* __restrict__ Wf2,
                     __bf16* __restrict__ wb) {
    __shared__ float t[8320];
    int m = blockIdx.x;
    const float* src; __bf16* dst; int R, C;
    if (m < 222) {
        int bank = m / 74;
        int r = m - bank * 74, op = r >> 1, which = r & 1;
        const float* s1[3] = {Wi1, Wc1, Wf1};
        const float* s2[3] = {Wi2, Wc2, Wf2};
        int obase[3] = {OFF_I, OFF_C, OFF_F};
        if (which == 0) { src = s1[bank] + op * 8192; R = 64;  C = 128; dst = wb + obase[bank] + op * 16384; }
        else            { src = s2[bank] + op * 8192; R = 128; C = 64;  dst = wb + obase[bank] + op * 16384 + 8192; }
    } else if (m < 286) {
        int bank = (m - 222) >> 5;
        int r = (m - 222) & 31, it = r >> 1, which = r & 1;
        const float* s1 = bank ? Wm1 : Wd1;
        const float* s2 = bank ? Wm2 : Wd2;
        int obase = bank ? OFF_M : OFF_D;
        if (which == 0) { src = s1 + it * 8192; R = 64;  C = 128; dst = wb + obase + it * 16384; }
        else            { src = s2 + it * 8192; R = 128; C = 64;  dst = wb + obase + it * 16384 + 8192; }
    } else {
        const float* q3[3] = {Wq, Wk, Wv};
        src = q3[m - 286]; R = 64; C = 64; dst = wb + OFF_QKV + (m - 286) * 4096;
    }
    int n = R * C, Cp = C + 1, logC = (C == 128) ? 7 : 6;
    for (int i = threadIdx.x; i < n; i += 256)
        t[(i >> logC) * Cp + (i & (C - 1))] = src[i];
    __syncthreads();
    int KF = R >> 5;
    int nfrag = n >> 3;
    for (int f = threadIdx.x; f < nfrag; f += 256) {
        int lane_ = f & 63, fk = f >> 6;
        int kf = fk & (KF - 1), nt = fk >> (KF == 2 ? 1 : 2);
        int lq_ = lane_ & 15, quad_ = lane_ >> 4;
        int col = nt * 16 + lq_;
        bfrag v;
        #pragma unroll
        for (int j = 0; j < 8; ++j) {
            int ks = kf * 32 + quad_ * 8 + j;
            int k = (R == 64) ? ((ks & 3) * 16 + (ks >> 2)) : ((ks & 7) * 16 + (ks >> 3));
            v[j] = (__bf16)t[k * Cp + col];
        }
        *(bfrag*)&dst[f * 8] = v;
    }
}

// ---------------- main kernel ----------------

__device__ __forceinline__ bfrag zfrag() {
    bfrag r;
    #pragma unroll
    for (int j = 0; j < 8; ++j) r[j] = (__bf16)0.0f;
    return r;
}

// XCD affinity: heavy ops one-per-XCD, op13 tile-spread, lights op&7
__device__ __forceinline__ int xcd_of(int o) {
    if (o <= 2) return o;
    if (o == 3) return 3;
    if (o == 4) return 4;
    if (o >= 10 && o <= 12) return o - 5;
    if (o == 13) return -1;          // spread across XCDs by tile
    return o & 7;
}

// stage both X tiles into XI and extract A-frags
__device__ __forceinline__ void stage_X(const float Xr[2][4][4], __bf16* XI,
                                        bfrag a[2][2], int lq, int quad) {
    #pragma unroll
    for (int mt = 0; mt < 2; ++mt)
        #pragma unroll
        for (int r = 0; r < 4; ++r) {
            bf16x4 v = { (__bf16)Xr[mt][0][r], (__bf16)Xr[mt][1][r],
                         (__bf16)Xr[mt][2][r], (__bf16)Xr[mt][3][r] };
            *(bf16x4*)&XI[(mt * 16 + quad * 4 + r) * 72 + lq * 4] = v;
        }
    #pragma unroll
    for (int mt = 0; mt < 2; ++mt)
        #pragma unroll
        for (int kf = 0; kf < 2; ++kf)
            a[mt][kf] = *(const bfrag*)&XI[(mt * 16 + lq) * 72 + kf * 32 + quad * 8];
}

// X[2 tiles][16 rows][64] += relu(X@W1+b1)@W2 + b2 ; each w frag -> 2 MFMAs
__device__ __forceinline__ void ffn_g4(float Xr[2][4][4], __bf16* XI, __bf16* H,
    const __bf16* __restrict__ w1, const __bf16* __restrict__ w2,
    const float* __restrict__ b1, const float* __restrict__ b2,
    int lane, int lq, int quad) {
    bfrag a[2][2];
    stage_X(Xr, XI, a, lq, quad);
    #pragma unroll
    for (int gg = 0; gg < 2; ++gg) {
        f32x4 acc[2][4];
        #pragma unroll
        for (int u = 0; u < 4; ++u) {
            float bv = b1[(gg * 4 + u) * 16 + lq];
            acc[0][u] = (f32x4){bv, bv, bv, bv};
            acc[1][u] = acc[0][u];
        }
        #pragma unroll
        for (int u = 0; u < 4; ++u) {
            int nt = gg * 4 + u;
            bfrag w0 = *(const bfrag*)(w1 + ((nt * 2 + 0) * 64 + lane) * 8);
            bfrag wz = *(const bfrag*)(w1 + ((nt * 2 + 1) * 64 + lane) * 8);
            acc[0][u] = MFMA16(a[0][0], w0, acc[0][u]);
            acc[0][u] = MFMA16(a[0][1], wz, acc[0][u]);
            acc[1][u] = MFMA16(a[1][0], w0, acc[1][u]);
            acc[1][u] = MFMA16(a[1][1], wz, acc[1][u]);
        }
        #pragma unroll
        for (int mt = 0; mt < 2; ++mt)
            #pragma unroll
            for (int r = 0; r < 4; ++r) {
                bf16x4 hv;
                #pragma unroll
                for (int u = 0; u < 4; ++u) hv[u] = (__bf16)fmaxf(acc[mt][u][r], 0.0f);
                *(bf16x4*)&H[(mt * 16 + quad * 4 + r) * 136 + lq * 8 + gg * 4] = hv;
            }
    }
    bfrag h[2][4];
    #pragma unroll
    for (int mt = 0; mt < 2; ++mt)
        #pragma unroll
        for (int kf = 0; kf < 4; ++kf)
            h[mt][kf] = *(const bfrag*)&H[(mt * 16 + lq) * 136 + kf * 32 + quad * 8];
    #pragma unroll
    for (int nt = 0; nt < 4; ++nt) {
        float bv = b2[nt * 16 + lq];
        f32x4 acc0 = (f32x4){bv, bv, bv, bv}, acc1 = acc0;
        #pragma unroll
        for (int kf = 0; kf < 4; ++kf) {
            bfrag w = *(const bfrag*)(w2 + ((nt * 4 + kf) * 64 + lane) * 8);
            acc0 = MFMA16(h[0][kf], w, acc0);
            acc1 = MFMA16(h[1][kf], w, acc1);
        }
        #pragma unroll
        for (int r = 0; r < 4; ++r) { Xr[0][nt][r] += acc0[r]; Xr[1][nt][r] += acc1[r]; }
    }
}

// residual attention, 2 chunks (one per tile); qkv frags shared across chunks
__device__ __forceinline__ void attn_g4(float Xr[2][4][4], __bf16* XI,
    __bf16* Qb, __bf16* Kb, __bf16* Vt, float* Sf, __bf16* Pp,
    const __bf16* __restrict__ qg, int lane, int lq, int quad) {
    bfrag a[2][2];
    stage_X(Xr, XI, a, lq, quad);
    #pragma unroll
    for (int c = 0; c < 2; ++c) {
        bfrag a0 = a[c][0], a1 = a[c][1];
        // Q projection
        {
            f32x4 acc[4];
            #pragma unroll
            for (int nt = 0; nt < 4; ++nt) {
                acc[nt] = (f32x4){0.f, 0.f, 0.f, 0.f};
                bfrag w0 = *(const bfrag*)(qg + ((nt * 2 + 0) * 64 + lane) * 8);
                bfrag w1 = *(const bfrag*)(qg + ((nt * 2 + 1) * 64 + lane) * 8);
                acc[nt] = MFMA16(a0, w0, acc[nt]);
                acc[nt] = MFMA16(a1, w1, acc[nt]);
            }
            #pragma unroll
            for (int r = 0; r < 4; ++r) {
                bf16x4 v = { (__bf16)acc[0][r], (__bf16)acc[1][r], (__bf16)acc[2][r], (__bf16)acc[3][r] };
                *(bf16x4*)&Qb[(quad * 4 + r) * 72 + lq * 4] = v;
            }
        }
        // K projection
        {
            f32x4 acc[4];
            #pragma unroll
            for (int nt = 0; nt < 4; ++nt) {
                acc[nt] = (f32x4){0.f, 0.f, 0.f, 0.f};
                bfrag w0 = *(const bfrag*)(qg + (((4 + nt) * 2 + 0) * 64 + lane) * 8);
                bfrag w1 = *(const bfrag*)(qg + (((4 + nt) * 2 + 1) * 64 + lane) * 8);
                acc[nt] = MFMA16(a0, w0, acc[nt]);
                acc[nt] = MFMA16(a1, w1, acc[nt]);
            }
            #pragma unroll
            for (int r = 0; r < 4; ++r) {
                bf16x4 v = { (__bf16)acc[0][r], (__bf16)acc[1][r], (__bf16)acc[2][r], (__bf16)acc[3][r] };
                *(bf16x4*)&Kb[(quad * 4 + r) * 72 + lq * 4] = v;
            }
        }
        // S = Q K^T * 1/8 (cross-slot entries garbage, never read)
        {
            bfrag q0 = *(const bfrag*)&Qb[lq * 72 + quad * 8];
            bfrag q1 = *(const bfrag*)&Qb[lq * 72 + 32 + quad * 8];
            bfrag k0 = *(const bfrag*)&Kb[lq * 72 + quad * 8];
            bfrag k1 = *(const bfrag*)&Kb[lq * 72 + 32 + quad * 8];
            f32x4 s = (f32x4){0.f, 0.f, 0.f, 0.f};
            s = MFMA16(q0, k0, s);
            s = MFMA16(q1, k1, s);
            #pragma unroll
            for (int r = 0; r < 4; ++r) Sf[(quad * 4 + r) * 20 + lq] = s[r] * 0.125f;
        }
        // softmax rows (lanes 0..15), block-diag P
        if (lane < 16) {
            int m = lane, base = (m >> 3) * 8;
            f32x4 t0 = *(const f32x4*)&Sf[m * 20 + base];
            f32x4 t1 = *(const f32x4*)&Sf[m * 20 + base + 4];
            float e[8];
            #pragma unroll
            for (int j = 0; j < 4; ++j) { e[j] = t0[j]; e[4 + j] = t1[j]; }
            float mx = e[0];
            #pragma unroll
            for (int j = 1; j < 8; ++j) mx = fmaxf(mx, e[j]);
            float sum = 0.f;
            #pragma unroll
            for (int j = 0; j < 8; ++j) { e[j] = __expf(e[j] - mx); sum += e[j]; }
            float inv = 1.0f / sum;
            bfrag lo = zfrag(), hi = zfrag();
            #pragma unroll
            for (int j = 0; j < 8; ++j) {
                __bf16 pv = (__bf16)(e[j] * inv);
                if (m < 8) lo[j] = pv; else hi[j] = pv;
            }
            *(bfrag*)&Pp[m * 24] = lo;
            *(bfrag*)&Pp[m * 24 + 8] = hi;
        }
        // V projection (Vt overlaps Qb/Kb, both consumed above)
        {
            f32x4 acc[4];
            #pragma unroll
            for (int nt = 0; nt < 4; ++nt) {
                acc[nt] = (f32x4){0.f, 0.f, 0.f, 0.f};
                bfrag w0 = *(const bfrag*)(qg + (((8 + nt) * 2 + 0) * 64 + lane) * 8);
                bfrag w1 = *(const bfrag*)(qg + (((8 + nt) * 2 + 1) * 64 + lane) * 8);
                acc[nt] = MFMA16(a0, w0, acc[nt]);
                acc[nt] = MFMA16(a1, w1, acc[nt]);
            }
            #pragma unroll
            for (int nt = 0; nt < 4; ++nt) {
                bf16x4 v = { (__bf16)acc[nt][0], (__bf16)acc[nt][1], (__bf16)acc[nt][2], (__bf16)acc[nt][3] };
                *(bf16x4*)&Vt[(nt * 16 + lq) * 24 + quad * 4] = v;
            }
        }
        // out += P @ V
        bfrag pa = zfrag();
        if (quad < 2) pa = *(const bfrag*)&Pp[lq * 24 + quad * 8];
        #pragma unroll
        for (int nt = 0; nt < 4; ++nt) {
            bfrag vb = zfrag();
            if (quad < 2) vb = *(const bfrag*)&Vt[(nt * 16 + lq) * 24 + quad * 8];
            f32x4 o = (f32x4){0.f, 0.f, 0.f, 0.f};
            o = MFMA16(pa, vb, o);
            #pragma unroll
            for (int r = 0; r < 4; ++r) Xr[c][nt][r] += o[r];
        }
    }
}

constexpr int PWSZ = 8832;   // per-wave LDS bytes

__global__ void __launch_bounds__(256, 3)
moe_main(const float* __restrict__ x, float* __restrict__ out,
         const int* __restrict__ cnt, const int* __restrict__ rowIdx,
         const __bf16* __restrict__ wb,
         const float* __restrict__ bi1, const float* __restrict__ bi2,
         const float* __restrict__ bc1, const float* __restrict__ bc2,
         const float* __restrict__ bd1, const float* __restrict__ bd2,
         const float* __restrict__ bm1, const float* __restrict__ bm2,
         const float* __restrict__ bf1_, const float* __restrict__ bf2_) {
    __shared__ __align__(16) unsigned char SM[4 * PWSZ];   // 35328 B -> 4 blocks/CU
    int lane = threadIdx.x & 63, wid = threadIdx.x >> 6;
    int lq = lane & 15, quad = lane >> 4;
    unsigned char* PW = SM + wid * PWSZ;
    __bf16* XI = (__bf16*)PW;              // [32][72] 4608 (dead after frag extract)
    __bf16* H  = (__bf16*)PW;              // [32][136] 8704 (FFN, over XI)
    __bf16* Qb = (__bf16*)PW;              // [16][72] 2304 (attn)
    __bf16* Kb = (__bf16*)(PW + 2304);     // [16][72]
    __bf16* Vt = (__bf16*)PW;              // [64][24] 3072 (over Qb/Kb after S)
    float*  Sf = (float*)(PW + 4608);      // [16][20] 1280
    __bf16* Pp = (__bf16*)(PW + 5888);     // [16][24] 768

    // block -> (op, tile): XCD-affine walk; 16 rows/block, 4/wave
    int g = blockIdx.x, xcd = g & 7, slot = g >> 3;
    int op = -1, tile = 0, acc = 0;
    for (int o = 0; o < NOPS; ++o) {
        int c = cnt[o]; if (c > CAP) c = CAP;
        int nt = (c + 15) >> 4;
        int xo = xcd_of(o);
        int mine = (xo < 0) ? ((nt > xcd) ? ((nt - 1 - xcd) >> 3) + 1 : 0)
                            : ((xo == xcd) ? nt : 0);
        if (mine && slot < acc + mine) {
            op = o;
            int j = slot - acc;
            tile = (xo < 0) ? (xcd + 8 * j) : j;
            break;
        }
        acc += mine;
    }
    if (op < 0) return;
    int c = cnt[op]; if (c > CAP) c = CAP;
    int rows[4];
    #pragma unroll
    for (int k = 0; k < 4; ++k) {
        int i = tile * 16 + wid * 4 + k;
        if (i > c - 1) i = c - 1;
        rows[k] = rowIdx[op * CAP + i];
    }

    // gather X into regs (C-layout): 64B-coalesced dword loads
    float Xr[2][4][4];
    #pragma unroll
    for (int mt = 0; mt < 2; ++mt) {
        const float* xb = x + (size_t)rows[mt * 2 + (quad >> 1)] * 512 + ((quad & 1) * 4) * 64;
        #pragma unroll
        for (int nt = 0; nt < 4; ++nt)
            #pragma unroll
            for (int r = 0; r < 4; ++r)
                Xr[mt][nt][r] = xb[r * 64 + nt * 16 + lq];
    }

    // Stage 1: initial experts
    ffn_g4(Xr, XI, H, wb + OFF_I + op * 16384, wb + OFF_I + op * 16384 + 8192,
           bi1 + op * 128, bi2 + op * 64, lane, lq, quad);
    // Stages 2-3: carry cascade
    bool carry = (op <= 2) || (op >= 10 && op <= 13);
    if (carry) {
        const __bf16* qg = wb + OFF_QKV;
        const __bf16* w1 = wb + OFF_C + op * 16384;
        const __bf16* w2 = w1 + 8192;
        for (int it = 0; it < 7; ++it) {
            attn_g4(Xr, XI, Qb, Kb, Vt, Sf, Pp, qg, lane, lq, quad);
            ffn_g4(Xr, XI, H, w1, w2, bc1 + op * 128, bc2 + op * 64, lane, lq, quad);
        }
    }
    // DIV / MOD iterative FFNs
    if (op == 3) {
        for (int i = 0; i < 16; ++i)
            ffn_g4(Xr, XI, H, wb + OFF_D + i * 16384, wb + OFF_D + i * 16384 + 8192,
                   bd1 + i * 128, bd2 + i * 64, lane, lq, quad);
    }
    if (op == 4) {
        for (int i = 0; i < 16; ++i)
            ffn_g4(Xr, XI, H, wb + OFF_M + i * 16384, wb + OFF_M + i * 16384 + 8192,
                   bm1 + i * 128, bm2 + i * 64, lane, lq, quad);
    }
    // Stage 4: final experts
    ffn_g4(Xr, XI, H, wb + OFF_F + op * 16384, wb + OFF_F + op * 16384 + 8192,
           bf1_ + op * 128, bf2_ + op * 64, lane, lq, quad);

    // scatter X regs to out (64B-coalesced; duplicate tail rows benign)
    #pragma unroll
    for (int mt = 0; mt < 2; ++mt) {
        float* ob = out + (size_t)rows[mt * 2 + (quad >> 1)] * 512 + ((quad & 1) * 4) * 64;
        #pragma unroll
        for (int nt = 0; nt < 4; ++nt)
            #pragma unroll
            for (int r = 0; r < 4; ++r)
                ob[r * 64 + nt * 16 + lq] = Xr[mt][nt][r];
    }
}

// ---------------- launch ----------------

extern "C" void kernel_launch(void* const* d_in, const int* in_sizes, int n_in,
                              void* d_out, int out_size, void* d_ws, size_t ws_size,
                              hipStream_t stream) {
    (void)in_sizes; (void)n_in; (void)out_size; (void)ws_size;
    const float* x   = (const float*)d_in[0];
    const float* Wi1 = (const float*)d_in[1];
    const float* bi1 = (const float*)d_in[2];
    const float* Wi2 = (const float*)d_in[3];
    const float* bi2 = (const float*)d_in[4];
    const float* Wq  = (const float*)d_in[5];
    const float* Wk  = (const float*)d_in[6];
    const float* Wv  = (const float*)d_in[7];
    const float* Wc1 = (const float*)d_in[8];
    const float* bc1 = (const float*)d_in[9];
    const float* Wc2 = (const float*)d_in[10];
    const float* bc2 = (const float*)d_in[11];
    const float* Wd1 = (const float*)d_in[12];
    const float* bd1 = (const float*)d_in[13];
    const float* Wd2 = (const float*)d_in[14];
    const float* bd2 = (const float*)d_in[15];
    const float* Wm1 = (const float*)d_in[16];
    const float* bm1 = (const float*)d_in[17];
    const float* Wm2 = (const float*)d_in[18];
    const float* bm2 = (const float*)d_in[19];
    const float* Wf1 = (const float*)d_in[20];
    const float* bf1 = (const float*)d_in[21];
    const float* Wf2 = (const float*)d_in[22];
    const float* bf2 = (const float*)d_in[23];
    float* out = (float*)d_out;

    int* wsi    = (int*)d_ws;
    int* cnt    = wsi + WS_CNT;
    int* rowIdx = wsi + WS_ROWIDX;
    __bf16* wb  = (__bf16*)((char*)d_ws + WB_BYTE);

    hipMemsetAsync(cnt, 0, 64 * sizeof(int), stream);
    k_route<<<NB / 4, 256, 0, stream>>>(x, cnt, rowIdx);
    k_wt<<<289, 256, 0, stream>>>(Wi1, Wi2, Wq, Wk, Wv, Wc1, Wc2, Wd1, Wd2,
                                  Wm1, Wm2, Wf1, Wf2, wb);
    // grid: 8 XCD lanes x worst-case slots per XCD
    int slots = (NB / 16) + NOPS;   // 1061
    moe_main<<<8 * slots, 256, 0, stream>>>(x, out, cnt, rowIdx, wb,
                                            bi1, bi2, bc1, bc2, bd1, bd2,
                                            bm1, bm2, bf1, bf2);
}

// Round 6
// 402.575 us; speedup vs baseline: 1.2262x; 1.2262x over previous
//
#include <hip/hip_runtime.h>
#include <math.h>

// SparseMoEALU R6: operand-swapped MFMA pipeline — state X kept transposed in
// registers (lane = row-slot, regs = d-channels), weights are the A-operand.
// Layer1 output H^T lands exactly in the layout layer2 consumes (hidden-dim
// permutation baked into pre-transformed weights) -> FFN has ZERO LDS and
// ZERO barriers. Reused weights (carry C, div/mod sets) are LDS-staged per
// block to kill the HBM re-fetch that bounded R4/R5. Heavy ops scheduled at
// low blockIdx so their long chains start first.

typedef __bf16 bfrag __attribute__((ext_vector_type(8)));
typedef float  f32x4 __attribute__((ext_vector_type(4)));

#define MFMA16(a,b,c) __builtin_amdgcn_mfma_f32_16x16x32_bf16((a),(b),(c),0,0,0)

constexpr int NB = 16384, NOPS = 37, OP_START = 16, CAP = 1024;

// ws ints: cnt[64] @0, rowIdx buckets @64 (37*1024)
constexpr int WS_CNT    = 0;
constexpr int WS_ROWIDX = 64;
constexpr int WB_BYTE   = 151808;     // weight region base (16B aligned)

// bf16 elem offsets in frag-major weight region
constexpr int OFF_QKV = 0;            // 3 x 4096 (Q,K,V)
constexpr int OFF_I   = 12288;        // 37 x (W1 8192 | W2 8192)
constexpr int OFF_C   = 618496;
constexpr int OFF_F   = 1224704;
constexpr int OFF_D   = 1830912;      // 16 x 16384
constexpr int OFF_M   = 2093056;

// heavy ops first: div, mod, carry {0,1,2,10,11,12,13}, then lights
__constant__ int ORD[37] = {3,4,0,1,2,10,11,12,13,5,6,7,8,9,14,15,16,17,18,
                            19,20,21,22,23,24,25,26,27,28,29,30,31,32,33,34,35,36};

// ---------------- prep kernels ----------------

__global__ void k_route(const float* __restrict__ x, int* __restrict__ cnt,
                        int* __restrict__ rowIdx) {
    int wave = threadIdx.x >> 6, lane = threadIdx.x & 63;
    int row = blockIdx.x * 4 + wave;
    if (row >= NB) return;
    float av = (lane < NOPS) ? x[(size_t)row * 512 + OP_START + lane] : -INFINITY;
    int ai = lane;
    #pragma unroll
    for (int s = 1; s < 64; s <<= 1) {
        float ov = __shfl_xor(av, s);
        int   oi = __shfl_xor(ai, s);
        if (ov > av || (ov == av && oi < ai)) { av = ov; ai = oi; }
    }
    if (lane == 0) {
        int t = atomicAdd(&cnt[ai], 1);
        if (t > CAP - 1) t = CAP - 1;
        rowIdx[ai * CAP + t] = row;
    }
}

// frag-major A-operand transform for W[K rows][N cols]:
// frag f = (nt*KF + kf)*64 + lane; elem jj = W[(2kf+(jj>>2))*16+quad*4+(jj&3)][nt*16+lq]
__global__ void k_wt(const float* __restrict__ Wi1, const float* __restrict__ Wi2,
                     const float* __restrict__ Wq,  const float* __restrict__ Wk,
                     const float* __restrict__ Wv,
                     const float* __restrict__ Wc1, const float* __restrict__ Wc2,
                     const float* __restrict__ Wd1, const float* __restrict__ Wd2,
                     const float* __restrict__ Wm1, const float* __restrict__ Wm2,
                     const float* __restrict__ Wf1, const float* __restrict__ Wf2,
                     __bf16* __restrict__ wb) {
    __shared__ float t[8320];
    int m = blockIdx.x;
    const float* src; __bf16* dst; int R, C;
    if (m < 222) {
        int bank = m / 74;                 // 0=I, 1=C, 2=F
        int r = m - bank * 74, op = r >> 1, which = r & 1;
        const float* s1[3] = {Wi1, Wc1, Wf1};
        const float* s2[3] = {Wi2, Wc2, Wf2};
        int ob[3] = {OFF_I, OFF_C, OFF_F};
        if (which == 0) { src = s1[bank] + op * 8192; R = 64;  C = 128; dst = wb + ob[bank] + op * 16384; }
        else            { src = s2[bank] + op * 8192; R = 128; C = 64;  dst = wb + ob[bank] + op * 16384 + 8192; }
    } else if (m < 286) {
        int bank = (m - 222) >> 5;         // 0=D, 1=M
        int r = (m - 222) & 31, it = r >> 1, which = r & 1;
        const float* s1 = bank ? Wm1 : Wd1;
        const float* s2 = bank ? Wm2 : Wd2;
        int ob = bank ? OFF_M : OFF_D;
        if (which == 0) { src = s1 + it * 8192; R = 64;  C = 128; dst = wb + ob + it * 16384; }
        else            { src = s2 + it * 8192; R = 128; C = 64;  dst = wb + ob + it * 16384 + 8192; }
    } else {
        const float* q3[3] = {Wq, Wk, Wv};
        src = q3[m - 286]; R = 64; C = 64; dst = wb + OFF_QKV + (m - 286) * 4096;
    }
    int n = R * C, Cp = C + 1, logC = (C == 128) ? 7 : 6;
    for (int i = threadIdx.x; i < n; i += 256)
        t[(i >> logC) * Cp + (i & (C - 1))] = src[i];
    __syncthreads();
    int KF = R >> 5, nfrag = n >> 3;
    for (int f = threadIdx.x; f < nfrag; f += 256) {
        int lane_ = f & 63, fk = f >> 6;
        int kf = fk % KF, nt = fk / KF;
        int lq_ = lane_ & 15, quad_ = lane_ >> 4;
        bfrag v;
        #pragma unroll
        for (int jj = 0; jj < 8; ++jj) {
            int krow = (2 * kf + (jj >> 2)) * 16 + quad_ * 4 + (jj & 3);
            v[jj] = (__bf16)t[krow * Cp + nt * 16 + lq_];
        }
        *(bfrag*)&dst[f * 8] = v;
    }
}

// ---------------- main kernel helpers ----------------

__device__ __forceinline__ bfrag zfrag() {
    bfrag r;
    #pragma unroll
    for (int j = 0; j < 8; ++j) r[j] = (__bf16)0.0f;
    return r;
}

// B-frag kf from 4 f32x4 regs in transposed layout (regs t = 2kf, 2kf+1)
__device__ __forceinline__ bfrag xfrag_of(const f32x4* Xn, int kf) {
    f32x4 a = Xn[2 * kf], b = Xn[2 * kf + 1];
    bfrag v;
    v[0] = (__bf16)a[0]; v[1] = (__bf16)a[1]; v[2] = (__bf16)a[2]; v[3] = (__bf16)a[3];
    v[4] = (__bf16)b[0]; v[5] = (__bf16)b[1]; v[6] = (__bf16)b[2]; v[7] = (__bf16)b[3];
    return v;
}

// X[2 n-tiles][4 d-regs] += relu(X@W1+b1)@W2 + b2 — all in registers
__device__ __forceinline__ void ffn_r(f32x4 X[2][4],
    const __bf16* __restrict__ w1, const __bf16* __restrict__ w2,
    const float* __restrict__ b1, const float* __restrict__ b2, int lane) {
    int quad = lane >> 4;
    bfrag xf[2][2];
    #pragma unroll
    for (int n = 0; n < 2; ++n)
        #pragma unroll
        for (int kf = 0; kf < 2; ++kf) xf[n][kf] = xfrag_of(X[n], kf);
    f32x4 H[2][8];
    #pragma unroll
    for (int jt = 0; jt < 8; ++jt) {
        f32x4 bi = *(const f32x4*)&b1[jt * 16 + quad * 4];
        H[0][jt] = bi; H[1][jt] = bi;
        #pragma unroll
        for (int kf = 0; kf < 2; ++kf) {
            bfrag w = *(const bfrag*)(w1 + ((jt * 2 + kf) * 64 + lane) * 8);
            H[0][jt] = MFMA16(w, xf[0][kf], H[0][jt]);
            H[1][jt] = MFMA16(w, xf[1][kf], H[1][jt]);
        }
    }
    #pragma unroll
    for (int dt = 0; dt < 4; ++dt) {
        f32x4 bv = *(const f32x4*)&b2[dt * 16 + quad * 4];
        X[0][dt] += bv; X[1][dt] += bv;
    }
    #pragma unroll
    for (int kf2 = 0; kf2 < 4; ++kf2) {
        bfrag hf0, hf1;
        {
            f32x4 a = H[0][2 * kf2], b = H[0][2 * kf2 + 1];
            hf0[0] = (__bf16)fmaxf(a[0], 0.f); hf0[1] = (__bf16)fmaxf(a[1], 0.f);
            hf0[2] = (__bf16)fmaxf(a[2], 0.f); hf0[3] = (__bf16)fmaxf(a[3], 0.f);
            hf0[4] = (__bf16)fmaxf(b[0], 0.f); hf0[5] = (__bf16)fmaxf(b[1], 0.f);
            hf0[6] = (__bf16)fmaxf(b[2], 0.f); hf0[7] = (__bf16)fmaxf(b[3], 0.f);
        }
        {
            f32x4 a = H[1][2 * kf2], b = H[1][2 * kf2 + 1];
            hf1[0] = (__bf16)fmaxf(a[0], 0.f); hf1[1] = (__bf16)fmaxf(a[1], 0.f);
            hf1[2] = (__bf16)fmaxf(a[2], 0.f); hf1[3] = (__bf16)fmaxf(a[3], 0.f);
            hf1[4] = (__bf16)fmaxf(b[0], 0.f); hf1[5] = (__bf16)fmaxf(b[1], 0.f);
            hf1[6] = (__bf16)fmaxf(b[2], 0.f); hf1[7] = (__bf16)fmaxf(b[3], 0.f);
        }
        #pragma unroll
        for (int dt = 0; dt < 4; ++dt) {
            bfrag w = *(const bfrag*)(w2 + ((dt * 4 + kf2) * 64 + lane) * 8);
            X[0][dt] = MFMA16(w, hf0, X[0][dt]);
            X[1][dt] = MFMA16(w, hf1, X[1][dt]);
        }
    }
}

// residual attention over the 8 positions of each row; Vl = per-wave LDS
// buffer [64 d-rows][pitch 24] bf16
__device__ __forceinline__ void attn_r(f32x4 X[2][4],
    const __bf16* __restrict__ qkv, __bf16* Vl, int lane) {
    int lq = lane & 15, quad = lane >> 4;
    int h = lq >> 3;
    bool qlow = (quad < 2);
    bool b1sel = (((quad >> 1) ^ h) != 0);
    bool b0 = ((quad & 1) != 0);
    #pragma unroll
    for (int c = 0; c < 2; ++c) {
        bfrag xf0 = xfrag_of(X[c], 0), xf1 = xfrag_of(X[c], 1);
        f32x4 Q[4], K[4], V[4];
        #pragma unroll
        for (int t = 0; t < 4; ++t) {
            Q[t] = (f32x4){0.f, 0.f, 0.f, 0.f}; K[t] = Q[t]; V[t] = Q[t];
            #pragma unroll
            for (int kf = 0; kf < 2; ++kf) {
                bfrag wq = *(const bfrag*)(qkv + ((t * 2 + kf) * 64 + lane) * 8);
                bfrag wk = *(const bfrag*)(qkv + 4096 + ((t * 2 + kf) * 64 + lane) * 8);
                bfrag wv = *(const bfrag*)(qkv + 8192 + ((t * 2 + kf) * 64 + lane) * 8);
                bfrag xx = kf ? xf1 : xf0;
                Q[t] = MFMA16(wq, xx, Q[t]);
                K[t] = MFMA16(wk, xx, K[t]);
                V[t] = MFMA16(wv, xx, V[t]);
            }
        }
        // V^T -> LDS [d_row][q]
        #pragma unroll
        for (int t = 0; t < 4; ++t)
            #pragma unroll
            for (int r = 0; r < 4; ++r)
                Vl[(t * 16 + quad * 4 + r) * 24 + lq] = (__bf16)V[t][r];
        // S^T = K-frags x Q-frags (lane holds col p=lq, rows q=quad*4+r)
        bfrag ka0 = xfrag_of(K, 0), ka1 = xfrag_of(K, 1);
        bfrag qb0 = xfrag_of(Q, 0), qb1 = xfrag_of(Q, 1);
        f32x4 s = (f32x4){0.f, 0.f, 0.f, 0.f};
        s = MFMA16(ka0, qb0, s);
        s = MFMA16(ka1, qb1, s);
        // gather the 8 scores of this column's row-block via butterfly
        float s8[8];
        #pragma unroll
        for (int r = 0; r < 4; ++r) {
            float v0 = s[r] * 0.125f;
            float v1 = __shfl_xor(v0, 16);
            float v2 = __shfl_xor(v0, 32);
            float v3 = __shfl_xor(v1, 32);
            float pl = b1sel ? v2 : v0;
            float ph = b1sel ? v3 : v1;
            s8[r]     = b0 ? ph : pl;
            s8[4 + r] = b0 ? pl : ph;
        }
        float mx = s8[0];
        #pragma unroll
        for (int j = 1; j < 8; ++j) mx = fmaxf(mx, s8[j]);
        float sum = 0.f;
        #pragma unroll
        for (int j = 0; j < 8; ++j) { s8[j] = __expf(s8[j] - mx); sum += s8[j]; }
        float inv = 1.0f / sum;
        bfrag pf = zfrag();
        if (quad == h) {
            #pragma unroll
            for (int jj = 0; jj < 8; ++jj) pf[jj] = (__bf16)(s8[jj] * inv);
        }
        // O^T = V(A, from LDS) x P(B); accumulates straight into X regs
        #pragma unroll
        for (int dt = 0; dt < 4; ++dt) {
            bfrag va = zfrag();
            if (qlow) va = *(const bfrag*)&Vl[(dt * 16 + lq) * 24 + quad * 8];
            f32x4 o = (f32x4){0.f, 0.f, 0.f, 0.f};
            o = MFMA16(va, pf, o);
            X[c][dt] += o;
        }
    }
}

// ---------------- main kernel ----------------

__global__ void __launch_bounds__(256, 3)
moe_main(const float* __restrict__ x, float* __restrict__ out,
         const int* __restrict__ cnt, const int* __restrict__ rowIdx,
         const __bf16* __restrict__ wb,
         const float* __restrict__ bi1, const float* __restrict__ bi2,
         const float* __restrict__ bc1, const float* __restrict__ bc2,
         const float* __restrict__ bd1, const float* __restrict__ bd2,
         const float* __restrict__ bm1, const float* __restrict__ bm2,
         const float* __restrict__ bf1_, const float* __restrict__ bf2_) {
    __shared__ __align__(16) __bf16 WL[16384];      // 32KB staged expert weights
    __shared__ __align__(16) __bf16 VB[4][1536];    // per-wave V buffers (3KB)

    int tid = threadIdx.x, lane = tid & 63, wid = tid >> 6;
    int lq = lane & 15, quad = lane >> 4;

    // heavy-first op walk: 16 rows/block, 4 rows/wave
    int g = blockIdx.x, op = -1, tile = 0, acc = 0;
    for (int idx = 0; idx < NOPS; ++idx) {
        int o = ORD[idx];
        int cc = cnt[o]; if (cc > CAP) cc = CAP;
        int nb = (cc + 15) >> 4;
        if (g < acc + nb) { op = o; tile = g - acc; break; }
        acc += nb;
    }
    if (op < 0) return;
    int c = cnt[op]; if (c > CAP) c = CAP;
    int rows[4];
    #pragma unroll
    for (int k = 0; k < 4; ++k) {
        int i = tile * 16 + wid * 4 + k;
        if (i > c - 1) i = c - 1;
        rows[k] = rowIdx[op * CAP + i];
    }

    // load X transposed: X[n][t] = x-rows of n-tile, d = t*16+quad*4+r, col m=lq
    f32x4 X[2][4];
    #pragma unroll
    for (int n = 0; n < 2; ++n) {
        const float* xb = x + (size_t)rows[n * 2 + (lq >> 3)] * 512 + (lq & 7) * 64 + quad * 4;
        #pragma unroll
        for (int t = 0; t < 4; ++t)
            X[n][t] = *(const f32x4*)&xb[t * 16];
    }

    // Stage 1: initial experts (global frags, L2-hot)
    const __bf16* wI = wb + OFF_I + op * 16384;
    ffn_r(X, wI, wI + 8192, bi1 + op * 128, bi2 + op * 64, lane);

    bool carry = (op <= 2) || (op >= 10 && op <= 13);
    if (carry) {
        // stage C expert into LDS once, reuse 7x
        const float4* s4 = (const float4*)(wb + OFF_C + op * 16384);
        float4* d4 = (float4*)WL;
        for (int i = tid; i < 2048; i += 256) d4[i] = s4[i];
        __syncthreads();
        const __bf16* qg = wb + OFF_QKV;
        const __bf16* cw = (const __bf16*)WL;
        for (int it = 0; it < 7; ++it) {
            attn_r(X, qg, &VB[wid][0], lane);
            ffn_r(X, cw, cw + 8192, bc1 + op * 128, bc2 + op * 64, lane);
        }
    } else if (op == 3 || op == 4) {
        const __bf16* base = wb + (op == 3 ? OFF_D : OFF_M);
        const float* bb1 = (op == 3) ? bd1 : bm1;
        const float* bb2 = (op == 3) ? bd2 : bm2;
        const float4* s4 = (const float4*)base;
        float4* d4 = (float4*)WL;
        for (int i = tid; i < 2048; i += 256) d4[i] = s4[i];
        __syncthreads();
        const __bf16* cw = (const __bf16*)WL;
        for (int it = 0; it < 16; ++it) {
            float4 tmp[8];
            if (it < 15) {
                const float4* nx = (const float4*)(base + (it + 1) * 16384);
                #pragma unroll
                for (int j = 0; j < 8; ++j) tmp[j] = nx[tid + j * 256];   // prefetch
            }
            ffn_r(X, cw, cw + 8192, bb1 + it * 128, bb2 + it * 64, lane);
            __syncthreads();
            if (it < 15) {
                #pragma unroll
                for (int j = 0; j < 8; ++j) d4[tid + j * 256] = tmp[j];
            }
            __syncthreads();
        }
    }

    // Stage 4: final experts
    const __bf16* wF = wb + OFF_F + op * 16384;
    ffn_r(X, wF, wF + 8192, bf1_ + op * 128, bf2_ + op * 64, lane);

    // store X (same transposed float4 pattern, fully coalesced per row)
    #pragma unroll
    for (int n = 0; n < 2; ++n) {
        float* ob = out + (size_t)rows[n * 2 + (lq >> 3)] * 512 + (lq & 7) * 64 + quad * 4;
        #pragma unroll
        for (int t = 0; t < 4; ++t)
            *(f32x4*)&ob[t * 16] = X[n][t];
    }
}

// ---------------- launch ----------------

extern "C" void kernel_launch(void* const* d_in, const int* in_sizes, int n_in,
                              void* d_out, int out_size, void* d_ws, size_t ws_size,
                              hipStream_t stream) {
    (void)in_sizes; (void)n_in; (void)out_size; (void)ws_size;
    const float* x   = (const float*)d_in[0];
    const float* Wi1 = (const float*)d_in[1];
    const float* bi1 = (const float*)d_in[2];
    const float* Wi2 = (const float*)d_in[3];
    const float* bi2 = (const float*)d_in[4];
    const float* Wq  = (const float*)d_in[5];
    const float* Wk  = (const float*)d_in[6];
    const float* Wv  = (const float*)d_in[7];
    const float* Wc1 = (const float*)d_in[8];
    const float* bc1 = (const float*)d_in[9];
    const float* Wc2 = (const float*)d_in[10];
    const float* bc2 = (const float*)d_in[11];
    const float* Wd1 = (const float*)d_in[12];
    const float* bd1 = (const float*)d_in[13];
    const float* Wd2 = (const float*)d_in[14];
    const float* bd2 = (const float*)d_in[15];
    const float* Wm1 = (const float*)d_in[16];
    const float* bm1 = (const float*)d_in[17];
    const float* Wm2 = (const float*)d_in[18];
    const float* bm2 = (const float*)d_in[19];
    const float* Wf1 = (const float*)d_in[20];
    const float* bf1 = (const float*)d_in[21];
    const float* Wf2 = (const float*)d_in[22];
    const float* bf2 = (const float*)d_in[23];
    float* out = (float*)d_out;

    int* wsi    = (int*)d_ws;
    int* cnt    = wsi + WS_CNT;
    int* rowIdx = wsi + WS_ROWIDX;
    __bf16* wb  = (__bf16*)((char*)d_ws + WB_BYTE);

    hipMemsetAsync(cnt, 0, 64 * sizeof(int), stream);
    k_route<<<NB / 4, 256, 0, stream>>>(x, cnt, rowIdx);
    k_wt<<<289, 256, 0, stream>>>(Wi1, Wi2, Wq, Wk, Wv, Wc1, Wc2, Wd1, Wd2,
                                  Wm1, Wm2, Wf1, Wf2, wb);
    moe_main<<<NB / 16 + NOPS, 256, 0, stream>>>(x, out, cnt, rowIdx, wb,
                                                 bi1, bi2, bc1, bc2, bd1, bd2,
                                                 bm1, bm2, bf1, bf2);
}